// Round 4
// baseline (1022.353 us; speedup 1.0000x reference)
//
#include <hip/hip_runtime.h>
#include <stdint.h>

#define B_     64
#define H_     16384
#define NB_    512
#define NNZ_   26214
#define N_IN_  1024
#define N_OUT_ 1024
#define SEG_   8      // segments per row (waves per row), full steps
#define SEG7_  32     // segments per row, last step (only 32 rows)

typedef __attribute__((ext_vector_type(8))) short    bf16x8;
typedef __attribute__((ext_vector_type(4))) float    f32x4;
typedef __attribute__((ext_vector_type(4))) unsigned int u32x4;

__device__ __forceinline__ unsigned short f2bf(float f) {
    union { unsigned int i; float f; } v; v.f = f;
    unsigned int x = v.i;
    return (unsigned short)((x + 0x7fffu + ((x >> 16) & 1u)) >> 16);
}

__device__ __forceinline__ bf16x8 ldfrag(const unsigned short* p) {
    union { u32x4 u; bf16x8 b; } cv;
    cv.u = *(const u32x4*)p;     // 16B aligned by construction
    return cv.b;
}

// ---------------- index build (tiny, graph-safe, redone every call) ---------

__global__ void zero_cnt(int* __restrict__ cnt) { cnt[threadIdx.x] = 0; }

__global__ void hist(const int* __restrict__ rows, int* __restrict__ cnt) {
    int n = blockIdx.x * 256 + threadIdx.x;
    if (n < NNZ_) atomicAdd(&cnt[rows[n]], 1);
}

__global__ void scan_k(int* __restrict__ cnt, int* __restrict__ ptr) {
    __shared__ int tmp[NB_];
    int t = threadIdx.x;
    tmp[t] = cnt[t];
    __syncthreads();
    for (int off = 1; off < NB_; off <<= 1) {
        int v = (t >= off) ? tmp[t - off] : 0;
        __syncthreads();
        tmp[t] += v;
        __syncthreads();
    }
    if (t == 0) ptr[0] = 0;
    ptr[t + 1] = tmp[t];
    cnt[t] = 0;
}

__global__ void scatter(const int* __restrict__ rows, const int* __restrict__ ptr,
                        int* __restrict__ cnt, int* __restrict__ perm) {
    int n = blockIdx.x * 256 + threadIdx.x;
    if (n < NNZ_) {
        int r = rows[n];
        int pos = ptr[r] + atomicAdd(&cnt[r], 1);
        perm[pos] = n;
    }
}

// ---------------- weights f32 -> bf16 (RNE), rerun every call ---------------

__global__ __launch_bounds__(256) void conv_w(const float* __restrict__ w,
                                              unsigned short* __restrict__ wb) {
    int idx = blockIdx.x * 256 + threadIdx.x;      // one float4 per thread
    float4 v = ((const float4*)w)[idx];
    union { unsigned short s[4]; uint2 d; } o;
    o.s[0] = f2bf(v.x); o.s[1] = f2bf(v.y); o.s[2] = f2bf(v.z); o.s[3] = f2bf(v.w);
    ((uint2*)wb)[idx] = o.d;
}

// ---------------- init: x_bf16 from inp (zero-padded), y = bias -------------

__global__ __launch_bounds__(256) void init_k(const float* __restrict__ inp,
                                              unsigned short* __restrict__ xb,
                                              float* __restrict__ y,
                                              const float* __restrict__ bias) {
    int idx = blockIdx.x * 256 + threadIdx.x;   // 0 .. B*H-1
    int b = idx >> 14;
    int h = idx & (H_ - 1);
    xb[idx] = (h < N_IN_) ? f2bf(inp[b * N_IN_ + h]) : (unsigned short)0;
    y[idx]  = bias[h];
}

// ---------------- MFMA accumulate ------------------------------------------
// One WAVE per (row r, segment sgi). No LDS, no barriers.
// Y^T[i][b] += sum W[i][k] * x[b][c*32+k]; M=i (32 = 2 tiles), N=b (64 = 4
// tiles), K=32. A-frag = 8 contiguous bf16 of W row; B-frag = 8 contiguous
// bf16 of x row. Flush via f32 atomicAdd into y (pre-initialized to bias).
__global__ __launch_bounds__(256) void accum_k(const unsigned short* __restrict__ xb,
                                               float* __restrict__ y,
                                               const unsigned short* __restrict__ wb,
                                               const int* __restrict__ cols,
                                               const int* __restrict__ perm,
                                               const int* __restrict__ ptr,
                                               int row_base, int col_limit, int nseg) {
    const int r    = blockIdx.x + row_base;
    const int wv   = threadIdx.x >> 6;            // wave in WG: 0..3
    const int sgi  = blockIdx.y * 4 + wv;         // global segment
    const int lane = threadIdx.x & 63;
    const int half = lane & 15;                   // n / m index within tile
    const int quad = lane >> 4;                   // k-group selector

    f32x4 acc[2][4] = {};                         // [mt][nt]

    const int beg = ptr[r], end = ptr[r + 1];
    bool did = false;                             // wave-uniform
    for (int k = beg + sgi; k < end; k += nseg) {
        const int n = perm[k];
        const int c = cols[n];
        if (c >= col_limit) continue;             // wave-uniform branch
        did = true;

        const unsigned short* wp = wb + (size_t)n * 1024 + quad * 8;
        bf16x8 a[2];
        a[0] = ldfrag(wp + half * 32);            // rows 0..15
        a[1] = ldfrag(wp + (16 + half) * 32);     // rows 16..31

        const unsigned short* xp = xb + (size_t)c * 32 + quad * 8;
        bf16x8 b[4];
        b[0] = ldfrag(xp + (size_t)(half)      * H_);
        b[1] = ldfrag(xp + (size_t)(16 + half) * H_);
        b[2] = ldfrag(xp + (size_t)(32 + half) * H_);
        b[3] = ldfrag(xp + (size_t)(48 + half) * H_);

        #pragma unroll
        for (int mt = 0; mt < 2; ++mt)
            #pragma unroll
            for (int nt = 0; nt < 4; ++nt)
                acc[mt][nt] = __builtin_amdgcn_mfma_f32_16x16x32_bf16(
                                  a[mt], b[nt], acc[mt][nt], 0, 0, 0);
    }

    if (!did) return;                             // wave-uniform

    // C/D layout: col(=batch within tile) = lane&15, row(=i) = quad*4+reg
    #pragma unroll
    for (int mt = 0; mt < 2; ++mt)
        #pragma unroll
        for (int nt = 0; nt < 4; ++nt)
            #pragma unroll
            for (int q2 = 0; q2 < 4; ++q2) {
                const int i = mt * 16 + quad * 4 + q2;
                const int b = nt * 16 + half;
                atomicAdd(&y[(size_t)b * H_ + r * 32 + i], acc[mt][nt][q2]);
            }
}

// ---------------- activation: x_bf16 = sigmoid(y); y = bias -----------------

__global__ __launch_bounds__(256) void act_k(float* __restrict__ y,
                                             unsigned short* __restrict__ xb,
                                             const float* __restrict__ bias) {
    int idx = blockIdx.x * 256 + threadIdx.x;
    int h = idx & (H_ - 1);
    float v = y[idx];
    xb[idx] = f2bf(1.0f / (1.0f + __expf(-v)));
    y[idx]  = bias[h];
}

// ---------------- final: out = sigmoid(y[:, -N_OUT:]) -----------------------

__global__ __launch_bounds__(256) void final_k(const float* __restrict__ y,
                                               float* __restrict__ out) {
    int idx = blockIdx.x * 256 + threadIdx.x;   // 0 .. B*N_OUT-1
    int b = idx >> 10;
    int k = idx & (N_OUT_ - 1);
    float v = y[(size_t)b * H_ + (H_ - N_OUT_) + k];
    out[idx] = 1.0f / (1.0f + __expf(-v));
}

// ---------------- launcher --------------------------------------------------

extern "C" void kernel_launch(void* const* d_in, const int* in_sizes, int n_in,
                              void* d_out, int out_size, void* d_ws, size_t ws_size,
                              hipStream_t stream) {
    const float* inp    = (const float*)d_in[0];
    const float* blocks = (const float*)d_in[1];
    const float* bias   = (const float*)d_in[2];
    const int*   rows   = (const int*)d_in[3];
    const int*   cols   = (const int*)d_in[4];
    float*       out    = (float*)d_out;

    char* ws = (char*)d_ws;
    unsigned short* wbf = (unsigned short*)ws;                       // 53.69 MB
    unsigned short* xbf = (unsigned short*)(ws + 53686272u);         // 2 MB
    float*          y   = (float*)(ws + 53686272u + 2097152u);       // 4 MB
    char*  idxbase      = ws + 53686272u + 2097152u + 4194304u;
    int*   rowptr = (int*)(idxbase);                                  // 513 ints
    int*   rowcnt = (int*)(idxbase + 4096);                           // 512 ints
    int*   perm   = (int*)(idxbase + 8192);                           // NNZ ints

    // index build
    zero_cnt<<<1, NB_, 0, stream>>>(rowcnt);
    hist<<<(NNZ_ + 255) / 256, 256, 0, stream>>>(rows, rowcnt);
    scan_k<<<1, NB_, 0, stream>>>(rowcnt, rowptr);
    scatter<<<(NNZ_ + 255) / 256, 256, 0, stream>>>(rows, rowptr, rowcnt, perm);

    // weights -> bf16 (NNZ*1024/4 float4s = 26214 blocks of 256)
    conv_w<<<NNZ_, 256, 0, stream>>>(blocks, wbf);

    init_k<<<(B_ * H_) / 256, 256, 0, stream>>>(inp, xbf, y, bias);

    // step 0: input nonzero only in first 32 col-blocks
    accum_k<<<dim3(NB_, SEG_ / 4), 256, 0, stream>>>(xbf, y, wbf, cols,
                                                     perm, rowptr, 0, 32, SEG_);
    act_k<<<(B_ * H_) / 256, 256, 0, stream>>>(y, xbf, bias);

    // steps 1..6
    for (int s = 1; s < 7; ++s) {
        accum_k<<<dim3(NB_, SEG_ / 4), 256, 0, stream>>>(xbf, y, wbf, cols,
                                                         perm, rowptr, 0, NB_, SEG_);
        act_k<<<(B_ * H_) / 256, 256, 0, stream>>>(y, xbf, bias);
    }

    // step 7: only rows 480..511 feed the output
    accum_k<<<dim3(N_OUT_ / 32, SEG7_ / 4), 256, 0, stream>>>(xbf, y, wbf, cols,
                                                              perm, rowptr,
                                                              NB_ - N_OUT_ / 32, NB_, SEG7_);
    final_k<<<(B_ * N_OUT_) / 256, 256, 0, stream>>>(y, out);
}

// Round 5
// 345.822 us; speedup vs baseline: 2.9563x; 2.9563x over previous
//
#include <hip/hip_runtime.h>
#include <stdint.h>

#define B_     64
#define H_     16384
#define NB_    512
#define NNZ_   26214
#define N_IN_  1024
#define N_OUT_ 1024

typedef __attribute__((ext_vector_type(8))) short    bf16x8;
typedef __attribute__((ext_vector_type(4))) float    f32x4;
typedef __attribute__((ext_vector_type(4))) unsigned int u32x4;

__device__ __forceinline__ unsigned short f2bf(float f) {
    union { unsigned int i; float f; } v; v.f = f;
    unsigned int x = v.i;
    return (unsigned short)((x + 0x7fffu + ((x >> 16) & 1u)) >> 16);
}

__device__ __forceinline__ bf16x8 ldfrag(const unsigned short* p) {
    union { u32x4 u; bf16x8 b; } cv;
    cv.u = *(const u32x4*)p;     // 16B aligned by construction
    return cv.b;
}

// ---------------- index build (tiny, graph-safe, redone every call) ---------

__global__ void zero_cnt(int* __restrict__ cnt) { cnt[threadIdx.x] = 0; }

__global__ void hist(const int* __restrict__ rows, int* __restrict__ cnt) {
    int n = blockIdx.x * 256 + threadIdx.x;
    if (n < NNZ_) atomicAdd(&cnt[rows[n]], 1);
}

__global__ void scan_k(int* __restrict__ cnt, int* __restrict__ ptr) {
    __shared__ int tmp[NB_];
    int t = threadIdx.x;
    tmp[t] = cnt[t];
    __syncthreads();
    for (int off = 1; off < NB_; off <<= 1) {
        int v = (t >= off) ? tmp[t - off] : 0;
        __syncthreads();
        tmp[t] += v;
        __syncthreads();
    }
    if (t == 0) ptr[0] = 0;
    ptr[t + 1] = tmp[t];
    cnt[t] = 0;
}

// writes packed (n, col) pairs sorted by row
__global__ void scatter2(const int* __restrict__ rows, const int* __restrict__ cols,
                         const int* __restrict__ ptr, int* __restrict__ cnt,
                         int2* __restrict__ pair2) {
    int n = blockIdx.x * 256 + threadIdx.x;
    if (n < NNZ_) {
        int r = rows[n];
        int pos = ptr[r] + atomicAdd(&cnt[r], 1);
        pair2[pos] = make_int2(n, cols[n]);
    }
}

// ---------------- weights f32 -> bf16 (RNE), rerun every call ---------------

__global__ __launch_bounds__(256) void conv_w(const float* __restrict__ w,
                                              unsigned short* __restrict__ wb) {
    int idx = blockIdx.x * 256 + threadIdx.x;      // one float4 per thread
    float4 v = ((const float4*)w)[idx];
    union { unsigned short s[4]; uint2 d; } o;
    o.s[0] = f2bf(v.x); o.s[1] = f2bf(v.y); o.s[2] = f2bf(v.z); o.s[3] = f2bf(v.w);
    ((uint2*)wb)[idx] = o.d;
}

// ---------------- init: x_bf16 from inp (zero-padded) -----------------------

__global__ __launch_bounds__(256) void init_x(const float* __restrict__ inp,
                                              unsigned short* __restrict__ xb) {
    int idx = blockIdx.x * 256 + threadIdx.x;   // 0 .. B*H-1
    int b = idx >> 14;
    int h = idx & (H_ - 1);
    xb[idx] = (h < N_IN_) ? f2bf(inp[b * N_IN_ + h]) : (unsigned short)0;
}

// ---------------- one step, one WG (4 waves) per row ------------------------
// Wave w handles a contiguous quarter of row r's blocks; ping-pong depth-1
// prefetch of MFMA fragments straight from global (no LDS staging, no
// barriers in the main loop). 4-wave reduce via padded LDS; epilogue fuses
// bias + sigmoid + bf16 pack, writing the next state (or f32 out if LAST).
#define MFMA8(A, Bv)                                                         \
    do {                                                                     \
        _Pragma("unroll")                                                    \
        for (int mt = 0; mt < 2; ++mt)                                       \
            _Pragma("unroll")                                                \
            for (int nt = 0; nt < 4; ++nt)                                   \
                acc[mt][nt] = __builtin_amdgcn_mfma_f32_16x16x32_bf16(       \
                                  A[mt], Bv[nt], acc[mt][nt], 0, 0, 0);      \
    } while (0)

template <bool LAST>
__global__ __launch_bounds__(256) void rowstep_k(
        const unsigned short* __restrict__ x,    // [B][H] bf16
        unsigned short* __restrict__ xout,       // [B][H] bf16 (next state)
        float* __restrict__ out,                 // [B][N_OUT] f32 (LAST only)
        const unsigned short* __restrict__ wb,   // [NNZ][32][32] bf16
        const float* __restrict__ bias,
        const int2* __restrict__ pair2,          // row-sorted (n, c)
        const int* __restrict__ ptr,
        int row_base, int col_limit) {
    __shared__ int2  s_pairs[4][64];
    __shared__ float s_red[4][64][33];           // [wave][b][i], padded

    const int r    = blockIdx.x + row_base;
    const int tid  = threadIdx.x;
    const int wv   = tid >> 6;
    const int lane = tid & 63;
    const int half = lane & 15;
    const int quad = lane >> 4;

    const int beg = ptr[r], cnt = ptr[r + 1] - beg;
    const int c0 = beg + (cnt * wv) / 4;
    const int m  = beg + (cnt * (wv + 1)) / 4 - c0;

    // lane-parallel pair fetch + ballot-compaction (filters c >= col_limit)
    int2 pc = make_int2(0, 0);
    bool valid = (lane < m);
    if (valid) pc = pair2[c0 + lane];
    valid = valid && (pc.y < col_limit);
    unsigned long long mask = __ballot(valid);
    if (valid) {
        int pos = __popcll(mask & ((1ull << lane) - 1ull));
        s_pairs[wv][pos] = pc;                   // intra-wave only: no barrier
    }
    const int mv = __popcll(mask);

    f32x4 acc[2][4] = {};

    bf16x8 A0[2], B0[4], A1[2], B1[4];
    #define LDFRAGS(A, Bv, p)                                                  \
        do {                                                                   \
            const unsigned short* wp =                                         \
                wb + (size_t)(p).x * 1024 + half * 32 + quad * 8;              \
            A[0] = ldfrag(wp);                                                 \
            A[1] = ldfrag(wp + 16 * 32);                                       \
            const unsigned short* xp =                                         \
                x + (size_t)(p).y * 32 + (size_t)half * H_ + quad * 8;         \
            Bv[0] = ldfrag(xp);                                                \
            Bv[1] = ldfrag(xp + (size_t)16 * H_);                              \
            Bv[2] = ldfrag(xp + (size_t)32 * H_);                              \
            Bv[3] = ldfrag(xp + (size_t)48 * H_);                              \
        } while (0)

    if (mv > 0) { int2 p = s_pairs[wv][0]; LDFRAGS(A0, B0, p); }
    int j = 0;
    while (j + 2 <= mv) {
        { int2 p = s_pairs[wv][j + 1]; LDFRAGS(A1, B1, p); }
        MFMA8(A0, B0);
        if (j + 2 < mv) { int2 p = s_pairs[wv][j + 2]; LDFRAGS(A0, B0, p); }
        MFMA8(A1, B1);
        j += 2;
    }
    if (j < mv) MFMA8(A0, B0);

    // dump accumulators: C/D layout col(b within tile)=lane&15, row(i)=quad*4+q
    #pragma unroll
    for (int mt = 0; mt < 2; ++mt)
        #pragma unroll
        for (int nt = 0; nt < 4; ++nt)
            #pragma unroll
            for (int q2 = 0; q2 < 4; ++q2)
                s_red[wv][nt * 16 + half][mt * 16 + quad * 4 + q2] = acc[mt][nt][q2];
    __syncthreads();

    // reduce 4 waves + bias + activation + store. t -> b = t>>2, i0 = (t&3)*8
    const int b  = tid >> 2;
    const int i0 = (tid & 3) * 8;
    float v[8];
    #pragma unroll
    for (int k = 0; k < 8; ++k)
        v[k] = s_red[0][b][i0 + k] + s_red[1][b][i0 + k]
             + s_red[2][b][i0 + k] + s_red[3][b][i0 + k]
             + bias[r * 32 + i0 + k];
    if (LAST) {
        #pragma unroll
        for (int k = 0; k < 8; ++k)
            out[(size_t)b * N_OUT_ + (r - (NB_ - N_OUT_ / 32)) * 32 + i0 + k]
                = 1.0f / (1.0f + __expf(-v[k]));
    } else {
        union { unsigned short s[8]; u32x4 u; } o;
        #pragma unroll
        for (int k = 0; k < 8; ++k)
            o.s[k] = f2bf(1.0f / (1.0f + __expf(-v[k])));
        *(u32x4*)(xout + (size_t)b * H_ + r * 32 + i0) = o.u;
    }
}

// ---------------- launcher --------------------------------------------------

extern "C" void kernel_launch(void* const* d_in, const int* in_sizes, int n_in,
                              void* d_out, int out_size, void* d_ws, size_t ws_size,
                              hipStream_t stream) {
    const float* inp    = (const float*)d_in[0];
    const float* blocks = (const float*)d_in[1];
    const float* bias   = (const float*)d_in[2];
    const int*   rows   = (const int*)d_in[3];
    const int*   cols   = (const int*)d_in[4];
    float*       out    = (float*)d_out;

    char* ws = (char*)d_ws;
    unsigned short* wbf = (unsigned short*)ws;                       // 53.69 MB
    unsigned short* x0  = (unsigned short*)(ws + 53686272u);         // 2 MB
    unsigned short* x1  = (unsigned short*)(ws + 53686272u + 2097152u);
    char*  idxbase      = ws + 53686272u + 2u * 2097152u;
    int*   rowptr = (int*)(idxbase);                                  // 513 ints
    int*   rowcnt = (int*)(idxbase + 4096);                           // 512 ints
    int2*  pair2  = (int2*)(idxbase + 8192);                          // NNZ int2

    // index build
    zero_cnt<<<1, NB_, 0, stream>>>(rowcnt);
    hist<<<(NNZ_ + 255) / 256, 256, 0, stream>>>(rows, rowcnt);
    scan_k<<<1, NB_, 0, stream>>>(rowcnt, rowptr);
    scatter2<<<(NNZ_ + 255) / 256, 256, 0, stream>>>(rows, cols, rowptr, rowcnt, pair2);

    // weights -> bf16
    conv_w<<<NNZ_, 256, 0, stream>>>(blocks, wbf);

    init_x<<<(B_ * H_) / 256, 256, 0, stream>>>(inp, x0);

    unsigned short* cur = x0;
    unsigned short* nxt = x1;
    // step 0: input nonzero only in first 32 col-blocks
    rowstep_k<false><<<NB_, 256, 0, stream>>>(cur, nxt, nullptr, wbf, bias,
                                              pair2, rowptr, 0, 32);
    { unsigned short* t = cur; cur = nxt; nxt = t; }
    // steps 1..6
    for (int s = 1; s < 7; ++s) {
        rowstep_k<false><<<NB_, 256, 0, stream>>>(cur, nxt, nullptr, wbf, bias,
                                                  pair2, rowptr, 0, NB_);
        unsigned short* t = cur; cur = nxt; nxt = t;
    }
    // step 7: only rows 480..511 feed the output; fused sigmoid -> f32 out
    rowstep_k<true><<<N_OUT_ / 32, 256, 0, stream>>>(cur, nullptr, out, wbf, bias,
                                                     pair2, rowptr,
                                                     NB_ - N_OUT_ / 32, NB_);
}

// Round 6
// 302.480 us; speedup vs baseline: 3.3799x; 1.1433x over previous
//
#include <hip/hip_runtime.h>
#include <stdint.h>

#define B_     64
#define H_     16384
#define NB_    512
#define NNZ_   26214
#define N_IN_  1024
#define N_OUT_ 1024

typedef __attribute__((ext_vector_type(8))) short    bf16x8;
typedef __attribute__((ext_vector_type(4))) float    f32x4;
typedef __attribute__((ext_vector_type(4))) unsigned int u32x4;

__device__ __forceinline__ unsigned short f2bf(float f) {
    union { unsigned int i; float f; } v; v.f = f;
    unsigned int x = v.i;
    return (unsigned short)((x + 0x7fffu + ((x >> 16) & 1u)) >> 16);
}

__device__ __forceinline__ bf16x8 ldfrag(const unsigned short* p) {
    union { u32x4 u; bf16x8 b; } cv;
    cv.u = *(const u32x4*)p;     // 16B aligned by construction
    return cv.b;
}

// ---------------- index build (tiny, graph-safe, redone every call) ---------

__global__ void zero_cnt(int* __restrict__ cnt) { cnt[threadIdx.x] = 0; }

__global__ void hist(const int* __restrict__ rows, int* __restrict__ cnt) {
    int n = blockIdx.x * 256 + threadIdx.x;
    if (n < NNZ_) atomicAdd(&cnt[rows[n]], 1);
}

__global__ void scan_k(int* __restrict__ cnt, int* __restrict__ ptr) {
    __shared__ int tmp[NB_];
    int t = threadIdx.x;
    tmp[t] = cnt[t];
    __syncthreads();
    for (int off = 1; off < NB_; off <<= 1) {
        int v = (t >= off) ? tmp[t - off] : 0;
        __syncthreads();
        tmp[t] += v;
        __syncthreads();
    }
    if (t == 0) ptr[0] = 0;
    ptr[t + 1] = tmp[t];
    cnt[t] = 0;
}

// writes packed (n, col) pairs sorted by row
__global__ void scatter2(const int* __restrict__ rows, const int* __restrict__ cols,
                         const int* __restrict__ ptr, int* __restrict__ cnt,
                         int2* __restrict__ pair2) {
    int n = blockIdx.x * 256 + threadIdx.x;
    if (n < NNZ_) {
        int r = rows[n];
        int pos = ptr[r] + atomicAdd(&cnt[r], 1);
        pair2[pos] = make_int2(n, cols[n]);
    }
}

// ---------------- weights f32 -> bf16 (RNE), rerun every call ---------------

__global__ __launch_bounds__(256) void conv_w(const float* __restrict__ w,
                                              unsigned short* __restrict__ wb) {
    int idx = blockIdx.x * 256 + threadIdx.x;      // one float4 per thread
    float4 v = ((const float4*)w)[idx];
    union { unsigned short s[4]; uint2 d; } o;
    o.s[0] = f2bf(v.x); o.s[1] = f2bf(v.y); o.s[2] = f2bf(v.z); o.s[3] = f2bf(v.w);
    ((uint2*)wb)[idx] = o.d;
}

// ---------------- init: blocked x[c][b][j] bf16 from inp (zero-padded) ------

__global__ __launch_bounds__(256) void init_x(const float* __restrict__ inp,
                                              unsigned short* __restrict__ xb) {
    int idx = blockIdx.x * 256 + threadIdx.x;   // 0 .. B*H-1 (blocked linear)
    int c = idx >> 11;          // 64*32 = 2048 elements per c-slab
    int b = (idx >> 5) & 63;
    int j = idx & 31;
    int h = c * 32 + j;
    xb[idx] = (h < N_IN_) ? f2bf(inp[b * N_IN_ + h]) : (unsigned short)0;
}

// ---------------- one step, one WG (8 waves) per row ------------------------
// x layout: [NB][64][32] bf16 (4KB contiguous slab per col-block -> B-frag
// loads are 1KB fully-used contiguous lines). Wave w handles 1/8 of row r's
// blocks, ping-pong depth-1 prefetch straight from global; 8-wave LDS reduce;
// epilogue fuses bias + sigmoid + bf16 pack into the next blocked state.
#define MFMA8(A, Bv)                                                         \
    do {                                                                     \
        _Pragma("unroll")                                                    \
        for (int mt = 0; mt < 2; ++mt)                                       \
            _Pragma("unroll")                                                \
            for (int nt = 0; nt < 4; ++nt)                                   \
                acc[mt][nt] = __builtin_amdgcn_mfma_f32_16x16x32_bf16(       \
                                  A[mt], Bv[nt], acc[mt][nt], 0, 0, 0);      \
    } while (0)

template <bool LAST>
__global__ __launch_bounds__(512, 4) void rowstep_k(
        const unsigned short* __restrict__ x,    // [NB][64][32] bf16 blocked
        unsigned short* __restrict__ xout,       // [NB][64][32] bf16 blocked
        float* __restrict__ out,                 // [B][N_OUT] f32 (LAST only)
        const unsigned short* __restrict__ wb,   // [NNZ][32][32] bf16
        const float* __restrict__ bias,
        const int2* __restrict__ pair2,          // row-sorted (n, c)
        const int* __restrict__ ptr,
        int row_base, int col_limit) {
    __shared__ int2  s_pairs[8][64];
    __shared__ float s_red[8][64][33];           // [wave][b][i], 67.6 KB

    const int r    = blockIdx.x + row_base;
    const int tid  = threadIdx.x;
    const int wv   = tid >> 6;                   // 0..7
    const int lane = tid & 63;
    const int half = lane & 15;
    const int quad = lane >> 4;

    const int beg = ptr[r], cnt = ptr[r + 1] - beg;
    const int c0 = beg + (cnt * wv) / 8;
    const int m  = beg + (cnt * (wv + 1)) / 8 - c0;

    // lane-parallel pair fetch + ballot-compaction (filters c >= col_limit)
    int2 pc = make_int2(0, 0);
    bool valid = (lane < m);
    if (valid) pc = pair2[c0 + lane];
    valid = valid && (pc.y < col_limit);
    unsigned long long mask = __ballot(valid);
    if (valid) {
        int pos = __popcll(mask & ((1ull << lane) - 1ull));
        s_pairs[wv][pos] = pc;                   // intra-wave only: no barrier
    }
    const int mv = __popcll(mask);

    f32x4 acc[2][4] = {};

    bf16x8 A0[2], B0[4], A1[2], B1[4];
    #define LDFRAGS(A, Bv, p)                                                  \
        do {                                                                   \
            const unsigned short* wp =                                         \
                wb + (size_t)(p).x * 1024 + half * 32 + quad * 8;              \
            A[0] = ldfrag(wp);                                                 \
            A[1] = ldfrag(wp + 16 * 32);                                       \
            const unsigned short* xp =                                         \
                x + ((size_t)(p).y * 64 + half) * 32 + quad * 8;               \
            Bv[0] = ldfrag(xp);                                                \
            Bv[1] = ldfrag(xp + 16 * 32);                                      \
            Bv[2] = ldfrag(xp + 32 * 32);                                      \
            Bv[3] = ldfrag(xp + 48 * 32);                                      \
        } while (0)

    if (mv > 0) { int2 p = s_pairs[wv][0]; LDFRAGS(A0, B0, p); }
    int j = 0;
    while (j + 2 <= mv) {
        { int2 p = s_pairs[wv][j + 1]; LDFRAGS(A1, B1, p); }
        MFMA8(A0, B0);
        if (j + 2 < mv) { int2 p = s_pairs[wv][j + 2]; LDFRAGS(A0, B0, p); }
        MFMA8(A1, B1);
        j += 2;
    }
    if (j < mv) MFMA8(A0, B0);

    // dump accumulators: C/D layout col(b within tile)=lane&15, row(i)=quad*4+q
    #pragma unroll
    for (int mt = 0; mt < 2; ++mt)
        #pragma unroll
        for (int nt = 0; nt < 4; ++nt)
            #pragma unroll
            for (int q2 = 0; q2 < 4; ++q2)
                s_red[wv][nt * 16 + half][mt * 16 + quad * 4 + q2] = acc[mt][nt][q2];
    __syncthreads();

    // reduce 8 waves + bias + activation + store. t -> b = t>>3, i0 = (t&7)*4
    const int b  = tid >> 3;
    const int i0 = (tid & 7) * 4;
    const float4 bv = *(const float4*)&bias[r * 32 + i0];
    float v[4] = {bv.x, bv.y, bv.z, bv.w};
    #pragma unroll
    for (int w = 0; w < 8; ++w)
        #pragma unroll
        for (int k = 0; k < 4; ++k)
            v[k] += s_red[w][b][i0 + k];
    if (LAST) {
        float4 o;
        o.x = 1.0f / (1.0f + __expf(-v[0]));
        o.y = 1.0f / (1.0f + __expf(-v[1]));
        o.z = 1.0f / (1.0f + __expf(-v[2]));
        o.w = 1.0f / (1.0f + __expf(-v[3]));
        *(float4*)&out[(size_t)b * N_OUT_ + (r - (NB_ - N_OUT_ / 32)) * 32 + i0] = o;
    } else {
        union { unsigned short s[4]; uint2 u; } o;
        #pragma unroll
        for (int k = 0; k < 4; ++k)
            o.s[k] = f2bf(1.0f / (1.0f + __expf(-v[k])));
        *(uint2*)&xout[((size_t)r * 64 + b) * 32 + i0] = o.u;
    }
}

// ---------------- launcher --------------------------------------------------

extern "C" void kernel_launch(void* const* d_in, const int* in_sizes, int n_in,
                              void* d_out, int out_size, void* d_ws, size_t ws_size,
                              hipStream_t stream) {
    const float* inp    = (const float*)d_in[0];
    const float* blocks = (const float*)d_in[1];
    const float* bias   = (const float*)d_in[2];
    const int*   rows   = (const int*)d_in[3];
    const int*   cols   = (const int*)d_in[4];
    float*       out    = (float*)d_out;

    char* ws = (char*)d_ws;
    unsigned short* wbf = (unsigned short*)ws;                       // 53.69 MB
    unsigned short* x0  = (unsigned short*)(ws + 53686272u);         // 2 MB
    unsigned short* x1  = (unsigned short*)(ws + 53686272u + 2097152u);
    char*  idxbase      = ws + 53686272u + 2u * 2097152u;
    int*   rowptr = (int*)(idxbase);                                  // 513 ints
    int*   rowcnt = (int*)(idxbase + 4096);                           // 512 ints
    int2*  pair2  = (int2*)(idxbase + 8192);                          // NNZ int2

    // index build
    zero_cnt<<<1, NB_, 0, stream>>>(rowcnt);
    hist<<<(NNZ_ + 255) / 256, 256, 0, stream>>>(rows, rowcnt);
    scan_k<<<1, NB_, 0, stream>>>(rowcnt, rowptr);
    scatter2<<<(NNZ_ + 255) / 256, 256, 0, stream>>>(rows, cols, rowptr, rowcnt, pair2);

    // weights -> bf16
    conv_w<<<NNZ_, 256, 0, stream>>>(blocks, wbf);

    init_x<<<(B_ * H_) / 256, 256, 0, stream>>>(inp, x0);

    unsigned short* cur = x0;
    unsigned short* nxt = x1;
    // step 0: input nonzero only in first 32 col-blocks
    rowstep_k<false><<<NB_, 512, 0, stream>>>(cur, nxt, nullptr, wbf, bias,
                                              pair2, rowptr, 0, 32);
    { unsigned short* t = cur; cur = nxt; nxt = t; }
    // steps 1..6
    for (int s = 1; s < 7; ++s) {
        rowstep_k<false><<<NB_, 512, 0, stream>>>(cur, nxt, nullptr, wbf, bias,
                                                  pair2, rowptr, 0, NB_);
        unsigned short* t = cur; cur = nxt; nxt = t;
    }
    // step 7: only rows 480..511 feed the output; fused sigmoid -> f32 out
    rowstep_k<true><<<N_OUT_ / 32, 512, 0, stream>>>(cur, nullptr, out, wbf, bias,
                                                     pair2, rowptr,
                                                     NB_ - N_OUT_ / 32, NB_);
}